// Round 1
// baseline (223.665 us; speedup 1.0000x reference)
//
#include <hip/hip_runtime.h>

#define N_SEG 100000
#define LUT_BITS 17
#define LUT_SIZE (1 << LUT_BITS)

// Build bucket LUT: lut[j] = largest i in [0, N_SEG) with xk[i] <= j*W
// (i.e. the segment containing bucket start j*W). One binary search per bucket.
__global__ void build_lut_kernel(const float* __restrict__ xk, int* __restrict__ lut) {
    int j = blockIdx.x * blockDim.x + threadIdx.x;
    if (j >= LUT_SIZE) return;
    float xe = xk[N_SEG];
    float W = xe / (float)LUT_SIZE;
    float target = (float)j * W;
    int lo = 0, hi = N_SEG;           // upper_bound over xstart = xk[0..N_SEG)
    while (lo < hi) {
        int mid = (lo + hi) >> 1;
        if (xk[mid] <= target) lo = mid + 1; else hi = mid;
    }
    int idx = lo - 1;
    if (idx < 0) idx = 0;
    lut[j] = idx;
}

template<bool USE_LUT>
__device__ __forceinline__ void eval_point(float x, float xe, float invW,
                                           const float* __restrict__ xk,
                                           const float* __restrict__ cp,
                                           const int* __restrict__ lut,
                                           float* v, float* idx_out) {
    // jnp.mod semantics: trunc-rem (exact fmod) then sign-adjust toward divisor sign.
    float r = fmodf(x, xe);
    if (r < 0.0f) r += xe;

    int idx;
    if (USE_LUT) {
        int j = (int)(r * invW);
        j = j < 0 ? 0 : (j > LUT_SIZE - 1 ? LUT_SIZE - 1 : j);
        idx = lut[j];
        // bidirectional fixup with searchsorted(side='right') semantics (<=)
        while (idx > 0 && xk[idx] > r) --idx;
        while (idx + 1 < N_SEG && xk[idx + 1] <= r) ++idx;
    } else {
        int lo = 0, hi = N_SEG;
        while (lo < hi) {
            int mid = (lo + hi) >> 1;
            if (xk[mid] <= r) lo = mid + 1; else hi = mid;
        }
        idx = lo - 1;
        if (idx < 0) idx = 0;
    }

    float x0 = xk[idx];
    float dx = xk[idx + 1] - x0;
    float s = (r - x0) / dx;

    float u  = 1.0f - s;
    float s2 = s * s, s3 = s2 * s;
    float u2 = u * u, u3 = u2 * u;
    float b0 = u3;
    float b1 = (3.0f * s) * u2;
    float b2 = (3.0f * s2) * u;
    float b3 = s3;

    const float4* p = reinterpret_cast<const float4*>(cp + (size_t)idx * 12);
    float4 pA = p[0];   // P0.x P0.y P0.z P1.x
    float4 pB = p[1];   // P1.y P1.z P2.x P2.y
    float4 pC = p[2];   // P2.z P3.x P3.y P3.z

    v[0] = b0 * pA.x + b1 * pA.w + b2 * pB.z + b3 * pC.y;
    v[1] = b0 * pA.y + b1 * pB.x + b2 * pB.w + b3 * pC.z;
    v[2] = b0 * pA.z + b1 * pB.y + b2 * pC.x + b3 * pC.w;
    *idx_out = (float)idx;
}

template<bool USE_LUT>
__global__ void __launch_bounds__(256)
eval_kernel(const float* __restrict__ xk,
            const float* __restrict__ cp,
            const float* __restrict__ xev,
            float* __restrict__ out_vals,
            float* __restrict__ out_idx,
            const int* __restrict__ lut,
            int npts) {
    int t = blockIdx.x * blockDim.x + threadIdx.x;
    int i0 = t * 4;
    if (i0 >= npts) return;

    float xe = xk[N_SEG];
    float invW = (float)LUT_SIZE / xe;

    if (i0 + 3 < npts) {
        // fast path: fully vectorized 4 points/thread
        float4 x4 = reinterpret_cast<const float4*>(xev)[t];
        float xs[4] = {x4.x, x4.y, x4.z, x4.w};
        float vals[12];
        float idxf[4];
        #pragma unroll
        for (int q = 0; q < 4; ++q) {
            eval_point<USE_LUT>(xs[q], xe, invW, xk, cp, lut, &vals[q * 3], &idxf[q]);
        }
        float4* ov = reinterpret_cast<float4*>(out_vals + (size_t)t * 12);
        ov[0] = make_float4(vals[0], vals[1], vals[2],  vals[3]);
        ov[1] = make_float4(vals[4], vals[5], vals[6],  vals[7]);
        ov[2] = make_float4(vals[8], vals[9], vals[10], vals[11]);
        reinterpret_cast<float4*>(out_idx)[t] = make_float4(idxf[0], idxf[1], idxf[2], idxf[3]);
    } else {
        // tail: scalar
        for (int i = i0; i < npts; ++i) {
            float v[3], idxf;
            eval_point<USE_LUT>(xev[i], xe, invW, xk, cp, lut, v, &idxf);
            out_vals[(size_t)i * 3 + 0] = v[0];
            out_vals[(size_t)i * 3 + 1] = v[1];
            out_vals[(size_t)i * 3 + 2] = v[2];
            out_idx[i] = idxf;
        }
    }
}

extern "C" void kernel_launch(void* const* d_in, const int* in_sizes, int n_in,
                              void* d_out, int out_size, void* d_ws, size_t ws_size,
                              hipStream_t stream) {
    const float* xk  = (const float*)d_in[0];   // x_knots, N_SEG+1
    const float* cp  = (const float*)d_in[1];   // control_points, N_SEG*4*3
    const float* xev = (const float*)d_in[2];   // x_eval, flat
    int npts = in_sizes[2];                     // 8,000,000

    float* out_vals = (float*)d_out;
    float* out_idx  = out_vals + (size_t)npts * 3;

    int nthreads = (npts + 3) / 4;
    int nblocks  = (nthreads + 255) / 256;

    bool use_lut = ws_size >= (size_t)LUT_SIZE * sizeof(int);
    if (use_lut) {
        int* lut = (int*)d_ws;
        build_lut_kernel<<<(LUT_SIZE + 255) / 256, 256, 0, stream>>>(xk, lut);
        eval_kernel<true><<<nblocks, 256, 0, stream>>>(xk, cp, xev, out_vals, out_idx, lut, npts);
    } else {
        eval_kernel<false><<<nblocks, 256, 0, stream>>>(xk, cp, xev, out_vals, out_idx, nullptr, npts);
    }
}